// Round 10
// baseline (372.878 us; speedup 1.0000x reference)
//
#include <hip/hip_runtime.h>
#include <math.h>

// OverlapTripletLoss: C=64 classes, K=64, ALPHA=1, N=131072, D=256, fp32.
// Pipeline:
//   prepK  : zero counters + convert mu -> bf16 hi/lo (global, L2-hot) + mu norms
//   countK/scanK/fillK : group points by label -> idxs[] (group-contiguous)
//   distK v3 : MFMA bf16x3-split GEMM (hi*hi + hi*lo + lo*hi, fp32 norms).
//            64 pts/wg, full-K row staging (one pass, full 128-B sectors),
//            ~68 KB LDS -> 2 wgs/CU, 2 barriers total, MFMA from LDS.
//   selK   : per (c,m) pair: exact top-64 mean via bisection on fp32 bit keys.
//   lossK  : sum over m!=c of max(1 + pos[c] - neg[m][c], 0) / N

#define DDIM 256
#define CC 64
#define KSEL 64
#define TPTS 64    // points per workgroup in distK v3
#define XS3 264    // LDS row stride (shorts): 528 B = 33*16 -> b128-aligned rows
#define SELN 2048

typedef short s4v __attribute__((ext_vector_type(4)));
typedef short s8v __attribute__((ext_vector_type(8)));
typedef float f4v __attribute__((ext_vector_type(4)));

__device__ __forceinline__ void cvt_split(float f, short& h, short& l) {
  const unsigned int u = __float_as_uint(f);
  const unsigned int hb = (u + 0x7FFFu + ((u >> 16) & 1u)) >> 16;   // RNE bf16
  h = (short)hb;
  const float rem = f - __uint_as_float(hb << 16);
  const unsigned int ur = __float_as_uint(rem);
  l = (short)((ur + 0x7FFFu + ((ur >> 16) & 1u)) >> 16);
}

// prepK: wg0 zeroes cnt/cnt2; all 16 wgs convert mu (64x256) to bf16 hi/lo and
// compute row norms. Row = b*4 + (t>>6); lane handles 4 consecutive values.
__global__ __launch_bounds__(256) void prepK(const float* __restrict__ mu, short* __restrict__ mhG,
                                             short* __restrict__ mlG, float* __restrict__ mn2G,
                                             int* __restrict__ cnts) {
  const int b = blockIdx.x, t = threadIdx.x;
  if (b == 0 && t < 128) cnts[t] = 0;
  const int row = b * 4 + (t >> 6), l = t & 63;
  const float4 v = *reinterpret_cast<const float4*>(mu + (size_t)row * DDIM + l * 4);
  const float vs[4] = {v.x, v.y, v.z, v.w};
  s4v hv, lv;
  float s2 = 0.f;
  #pragma unroll
  for (int j = 0; j < 4; ++j) {
    short hj, lj; cvt_split(vs[j], hj, lj);
    hv[j] = hj; lv[j] = lj;
    s2 = fmaf(vs[j], vs[j], s2);
  }
  *reinterpret_cast<s4v*>(&mhG[(size_t)row * DDIM + l * 4]) = hv;
  *reinterpret_cast<s4v*>(&mlG[(size_t)row * DDIM + l * 4]) = lv;
  #pragma unroll
  for (int off = 32; off > 0; off >>= 1) s2 += __shfl_xor(s2, off, 64);
  if (l == 0) mn2G[row] = s2;
}

__global__ __launch_bounds__(256) void countK(const int* __restrict__ y, int* cnt, int N) {
  int i = blockIdx.x * 256 + threadIdx.x;
  if (i < N) atomicAdd(&cnt[y[3 * i + 2] & (CC - 1)], 1);
}

__global__ void scanK(const int* __restrict__ cnt, int* base) {
  if (threadIdx.x == 0) {
    int s = 0;
    for (int i = 0; i < CC; ++i) { base[i] = s; s += cnt[i]; }
  }
}

__global__ __launch_bounds__(256) void fillK(const int* __restrict__ y, const int* __restrict__ base,
                                             int* cnt2, int* idxs, int N) {
  int i = blockIdx.x * 256 + threadIdx.x;
  if (i < N) {
    int m = y[3 * i + 2] & (CC - 1);
    int r = atomicAdd(&cnt2[m], 1);      // order within group is irrelevant
    idxs[base[m] + r] = i;
  }
}

// MFMA distance kernel v3. Per wg: 64 group-ordered points x all 64 centroids.
// Phase 1 (one pass over x): stage full 256-dim rows as bf16 hi/lo in LDS.
//   Per wave-instruction: 8 rows x 128 B contiguous -> full HBM sectors.
// Phase 2: 8 K-chunks of MFMA straight from LDS; A=mu frags from global
//   (mhG/mlG, 64 KB L2-hot, exact 64-B sectors per lk-quad). 2 barriers total.
// Wave w owns points [16w,16w+16) (1 n-tile) x 64 centroids (4 m-tiles).
// Verified gfx950 16x16x32 mapping: a/b lane l -> (idx=l&15, k=(l>>4)*8+e);
// D lane l reg r -> (row=(l>>4)*4+r, col=l&15).
__global__ __launch_bounds__(256, 2) void distK(const float* __restrict__ x, const short* __restrict__ mhG,
                                                const short* __restrict__ mlG, const float* __restrict__ mn2G,
                                                const int* __restrict__ idxs, float* __restrict__ Dg, int N) {
  __shared__ __align__(16) short xh[TPTS][XS3];
  __shared__ __align__(16) short xl[TPTS][XS3];
  __shared__ int pid[TPTS];
  __shared__ float xn2[TPTS];

  const int t = threadIdx.x;
  const int wgp0 = blockIdx.x * TPTS;
  if (t < TPTS) pid[t] = idxs[wgp0 + t];

  const int w = t >> 6, l = t & 63;     // wave, lane
  const int lr = l & 15, lk = l >> 4;   // frag idx, k-group
  const int c8 = t & 7;                 // staging: chunk-lane within row

  __syncthreads();                      // pid visible

  // ---- phase 1: stage x rows once (2 passes of 32 rows) ----
  #pragma unroll
  for (int pass = 0; pass < 2; ++pass) {
    const int row = pass * 32 + (t >> 3);
    const size_t rbase = (size_t)pid[row] * DDIM;
    float s2 = 0.f;
    #pragma unroll
    for (int j = 0; j < 8; ++j) {
      const int fi = (c8 + 8 * j) * 4;  // lanes 0..7 -> 128 B contiguous
      const float4 v = *reinterpret_cast<const float4*>(x + rbase + fi);
      const float vs[4] = {v.x, v.y, v.z, v.w};
      s4v hv, lv;
      #pragma unroll
      for (int jj = 0; jj < 4; ++jj) {
        short hj, lj; cvt_split(vs[jj], hj, lj);
        hv[jj] = hj; lv[jj] = lj;
        s2 = fmaf(vs[jj], vs[jj], s2);
      }
      *reinterpret_cast<s4v*>(&xh[row][fi]) = hv;
      *reinterpret_cast<s4v*>(&xl[row][fi]) = lv;
    }
    s2 += __shfl_xor(s2, 1, 64); s2 += __shfl_xor(s2, 2, 64); s2 += __shfl_xor(s2, 4, 64);
    if (c8 == 0) xn2[row] = s2;
  }
  __syncthreads();                      // staging + norms visible

  // ---- phase 2: 8 K-chunks of MFMA from LDS ----
  f4v acc[4];
  #pragma unroll
  for (int a = 0; a < 4; ++a) acc[a] = (f4v)0.f;
  const int prow = w * 16 + lr;

  #pragma unroll
  for (int ch = 0; ch < 8; ++ch) {
    const int kb = ch * 32;
    s8v ah[4], al_[4];
    #pragma unroll
    for (int mt = 0; mt < 4; ++mt) {
      const size_t ro = (size_t)(mt * 16 + lr) * DDIM + kb + lk * 8;
      ah[mt]  = *reinterpret_cast<const s8v*>(mhG + ro);
      al_[mt] = *reinterpret_cast<const s8v*>(mlG + ro);
    }
    const s8v bh = *reinterpret_cast<const s8v*>(&xh[prow][kb + lk * 8]);
    const s8v bl = *reinterpret_cast<const s8v*>(&xl[prow][kb + lk * 8]);
    // term-major: 4 independent acc chains per term
    #pragma unroll
    for (int mt = 0; mt < 4; ++mt)
      acc[mt] = __builtin_amdgcn_mfma_f32_16x16x32_bf16(ah[mt], bh, acc[mt], 0, 0, 0);
    #pragma unroll
    for (int mt = 0; mt < 4; ++mt)
      acc[mt] = __builtin_amdgcn_mfma_f32_16x16x32_bf16(ah[mt], bl, acc[mt], 0, 0, 0);
    #pragma unroll
    for (int mt = 0; mt < 4; ++mt)
      acc[mt] = __builtin_amdgcn_mfma_f32_16x16x32_bf16(al_[mt], bh, acc[mt], 0, 0, 0);
  }

  // ---- epilogue: d = sqrt(max(|mu|^2 + |x|^2 - 2*dot, 0)) ----
  const float xn = xn2[prow];
  #pragma unroll
  for (int mt = 0; mt < 4; ++mt) {
    #pragma unroll
    for (int r = 0; r < 4; ++r) {
      const int m = mt * 16 + lk * 4 + r;
      const float d2 = mn2G[m] + xn - 2.f * acc[mt][r];
      Dg[(size_t)m * N + wgp0 + prow] = sqrtf(fmaxf(d2, 0.f));
    }
  }
}

// Selection: one wg (128 thr) per (c,m). Exact top-64 via bisection on fp32 bit
// space. Distances are >= 0 so bits(v) is order-isomorphic to v; diag uses
// ~bits(v) (order-reversing) so "64 smallest keys" = 64 largest values.
// Exact with ties: sum = sum_{key<kth} val + (KSEL - cnt_less) * val(kth).
__global__ __launch_bounds__(128) void selK(const float* __restrict__ Dg, const int* __restrict__ cnt,
                                            const int* __restrict__ base, float* __restrict__ posM,
                                            float* __restrict__ neg, int N) {
  __shared__ __align__(16) unsigned int keys[SELN];
  __shared__ unsigned int sh_lo, sh_hi;
  __shared__ int sh_cnt[2];
  __shared__ float sh_sum[2];
  const int c = blockIdx.x, m = blockIdx.y;
  const int t = threadIdx.x;
  const int w = t >> 6, lane = t & 63;
  const bool diag = (c == m);
  int cm = cnt[m]; if (cm > SELN) cm = SELN;
  const int bm = base[m];
  const float* src = Dg + (size_t)c * N + bm;
  const int cm4 = (cm + 3) & ~3;

  unsigned int kmin = 0xFFFFFFFFu, kmax = 0u;
  for (int i = t; i < cm4; i += 128) {
    unsigned int key = 0xFFFFFFFFu;
    if (i < cm) {
      const unsigned int b = __float_as_uint(src[i]);
      key = diag ? ~b : b;
      kmin = min(kmin, key); kmax = max(kmax, key);
    }
    keys[i] = key;
  }
  #pragma unroll
  for (int off = 32; off > 0; off >>= 1) {
    kmin = min(kmin, (unsigned int)__shfl_xor((int)kmin, off, 64));
    kmax = max(kmax, (unsigned int)__shfl_xor((int)kmax, off, 64));
  }
  if (lane == 0) { sh_cnt[w] = (int)kmin; sh_sum[w] = __uint_as_float(kmax); }
  __syncthreads();
  if (t == 0) {
    sh_lo = min((unsigned int)sh_cnt[0], (unsigned int)sh_cnt[1]);
    sh_hi = max(__float_as_uint(sh_sum[0]), __float_as_uint(sh_sum[1]));
  }

  for (;;) {
    __syncthreads();
    const unsigned int lo = sh_lo, hi = sh_hi;
    if (lo >= hi) break;
    const unsigned int mid = lo + ((hi - lo) >> 1);
    int cl = 0;
    for (int i4 = t * 4; i4 < cm4; i4 += 512) {
      const uint4 kv = *reinterpret_cast<const uint4*>(&keys[i4]);
      cl += (int)(kv.x <= mid) + (int)(kv.y <= mid) + (int)(kv.z <= mid) + (int)(kv.w <= mid);
    }
    #pragma unroll
    for (int off = 32; off > 0; off >>= 1) cl += __shfl_xor(cl, off, 64);
    if (lane == 0) sh_cnt[w] = cl;
    __syncthreads();
    if (t == 0) {
      if (sh_cnt[0] + sh_cnt[1] >= KSEL) sh_hi = mid; else sh_lo = mid + 1;
    }
  }
  const unsigned int kth = sh_lo;

  int cl = 0; float sl = 0.f;
  for (int i4 = t * 4; i4 < cm4; i4 += 512) {
    const uint4 kv = *reinterpret_cast<const uint4*>(&keys[i4]);
    const unsigned int ks[4] = {kv.x, kv.y, kv.z, kv.w};
    #pragma unroll
    for (int j = 0; j < 4; ++j) {
      if (ks[j] < kth) { ++cl; sl += __uint_as_float(diag ? ~ks[j] : ks[j]); }
    }
  }
  #pragma unroll
  for (int off = 32; off > 0; off >>= 1) {
    cl += __shfl_xor(cl, off, 64);
    sl += __shfl_xor(sl, off, 64);
  }
  if (lane == 0) { sh_cnt[w] = cl; sh_sum[w] = sl; }
  __syncthreads();
  if (t == 0) {
    const int totc = sh_cnt[0] + sh_cnt[1];
    const float tots = sh_sum[0] + sh_sum[1];
    const float kval = __uint_as_float(diag ? ~kth : kth);
    const float mval = (tots + (float)(KSEL - totc) * kval) * (1.0f / KSEL);
    if (diag) posM[c] = mval; else neg[m * CC + c] = mval;
  }
}

__global__ __launch_bounds__(256) void lossK(const float* __restrict__ posM, const float* __restrict__ neg,
                                             float* __restrict__ out, int N) {
  __shared__ float red[256];
  const int t = threadIdx.x;
  float s = 0.f;
  for (int idx = t; idx < CC * CC; idx += 256) {
    const int m = idx >> 6, c = idx & 63;
    if (m != c) {
      const float h = 1.0f + posM[c] - neg[idx];
      s += fmaxf(h, 0.0f);
    }
  }
  red[t] = s;
  __syncthreads();
  for (int off = 128; off > 0; off >>= 1) {
    if (t < off) red[t] += red[t + off];
    __syncthreads();
  }
  if (t == 0) out[0] = red[0] / (float)N;
}

__global__ void wsFailK(float* out) {
  if (threadIdx.x == 0) out[0] = -1.0e30f;  // sentinel: workspace too small
}

extern "C" void kernel_launch(void* const* d_in, const int* in_sizes, int n_in,
                              void* d_out, int out_size, void* d_ws, size_t ws_size,
                              hipStream_t stream) {
  const float* x  = (const float*)d_in[0];
  const int*   y  = (const int*)d_in[1];
  const float* mu = (const float*)d_in[2];
  float* out = (float*)d_out;
  const int N = in_sizes[0] / DDIM;

  // Workspace layout (bytes):
  //   0: cnt[64], 256: cnt2[64], 512: base[64], 768: posM[64],
  //   1024: neg[4096] (16 KB), 17408: mn2G[64], 20480: mhG[64*256] bf16 (32 KB),
  //   53248: mlG (32 KB), 131072: idxs[N] (512 KB), 655360: Dg[64*N] (32 MB)
  const size_t need = (size_t)655360 + (size_t)CC * (size_t)N * 4;
  if (ws_size < need) {  // refuse to write OOB; emit sentinel (deterministic)
    hipLaunchKernelGGL(wsFailK, dim3(1), dim3(64), 0, stream, out);
    return;
  }
  char* w = (char*)d_ws;
  int*   cnt  = (int*)(w);
  int*   cnt2 = (int*)(w + 256);
  int*   base = (int*)(w + 512);
  float* posM = (float*)(w + 768);
  float* neg  = (float*)(w + 1024);
  float* mn2G = (float*)(w + 17408);
  short* mhG  = (short*)(w + 20480);
  short* mlG  = (short*)(w + 53248);
  int*   idxs = (int*)(w + 131072);
  float* Dg   = (float*)(w + 655360);

  hipLaunchKernelGGL(prepK, dim3(16), dim3(256), 0, stream, mu, mhG, mlG, mn2G, cnt);
  hipLaunchKernelGGL(countK, dim3((N + 255) / 256), dim3(256), 0, stream, y, cnt, N);
  hipLaunchKernelGGL(scanK, dim3(1), dim3(64), 0, stream, cnt, base);
  hipLaunchKernelGGL(fillK, dim3((N + 255) / 256), dim3(256), 0, stream, y, base, cnt2, idxs, N);
  hipLaunchKernelGGL(distK, dim3(N / TPTS), dim3(256), 0, stream, x, mhG, mlG, mn2G, idxs, Dg, N);
  hipLaunchKernelGGL(selK, dim3(CC, CC), dim3(128), 0, stream, Dg, cnt, base, posM, neg, N);
  hipLaunchKernelGGL(lossK, dim3(1), dim3(256), 0, stream, posM, neg, out, N);
}